// Round 6
// baseline (304.988 us; speedup 1.0000x reference)
//
#include <hip/hip_runtime.h>
#include <math.h>

#define NB    16
#define NPTS  2048
#define NT    512
#define CROWS 1024           // rows per LDS transpose chunk
#define LPC   1028           // chunk pitch in floats (float4-aligned, +4 pad)
#define EPSB  1e-5f

struct KArgs {
    const float *x;
    const float *fc1_w, *fc1_b, *bn1_g, *bn1_b;
    const float *fc2_w, *fc2_b, *bn2_g, *bn2_b;
    const float *fc3_w, *fc3_b;
    const float *uw0, *ub0, *ps0, *ph0, *wr0;
    const float *uw1, *ub1, *ps1, *ph1, *wr1;
    const float *uw2, *ub2, *ps2, *ph2, *wr2;
    const float *uw3, *ub3, *ps3, *ph3, *wr3;
    const float *fc4_w, *fc4_b, *bn4_g, *bn4_b;
    const float *fc5_w, *fc5_b, *fc6_w, *fc6_b, *fc7_w, *fc7_b;
    int    *cnt;          // single arrive counter (pre-zeroed)
    float2 *G;            // [NPTS][NB] bn4 stat partials (s,q)
    float  *out;
};

// ---------------------------------------------------------------------------
// One block per batch; thread owns rows n0..n0+3 (consecutive) in registers
// through encoder + all 4 relmods. M-reductions are intra-block (LDS only).
// Single device-wide barrier before bn4 (the only cross-batch coupling).
// ---------------------------------------------------------------------------
__global__ __launch_bounds__(NT, 1) void relnet_one(KArgs a)
{
    __shared__ float w1[18], b1[6], w2[72], b2[12], w3[144], b3[12];
    __shared__ float Wu[4][144], Bu[4][12];
    __shared__ float w4[72], b4[6], w5[18], b5[3], w6[3], w7[6], hb[3], scc[4];
    __shared__ float xT[12 * LPC], uT[12 * LPC];   // 98.7 KB
    __shared__ float Part[8][4][36], Ml[144];

    const int tid   = threadIdx.x;
    const int batch = blockIdx.x;
    const int n0    = tid * 4;                     // 4 consecutive rows
    const int lane  = tid & 63;
    const int wv    = tid >> 6;

    // ---- weights -> LDS
    if (tid < 144) {
        w3[tid] = a.fc3_w[tid];
        Wu[0][tid] = a.uw0[tid]; Wu[1][tid] = a.uw1[tid];
        Wu[2][tid] = a.uw2[tid]; Wu[3][tid] = a.uw3[tid];
    }
    if (tid < 18) { w1[tid] = a.fc1_w[tid]; w5[tid] = a.fc5_w[tid]; }
    if (tid < 6)  { b1[tid] = a.fc1_b[tid]; b4[tid] = a.fc4_b[tid]; w7[tid] = a.fc7_w[tid]; }
    if (tid < 72) { w2[tid] = a.fc2_w[tid]; w4[tid] = a.fc4_w[tid]; }
    if (tid < 12) {
        b2[tid] = a.fc2_b[tid]; b3[tid] = a.fc3_b[tid];
        Bu[0][tid] = a.ub0[tid]; Bu[1][tid] = a.ub1[tid];
        Bu[2][tid] = a.ub2[tid]; Bu[3][tid] = a.ub3[tid];
    }
    if (tid < 3)  { b5[tid] = a.fc5_b[tid]; w6[tid] = a.fc6_w[tid]; }
    if (tid == 0) { hb[0] = a.fc6_b[0]; hb[1] = a.fc7_b[0]; hb[2] = a.fc7_b[1]; }
    if (tid >= 4 && tid < 8) {
        const int r = tid - 4; float p, h, w;
        if      (r == 0) { p = a.ps0[0]; h = a.ph0[0]; w = a.wr0[0]; }
        else if (r == 1) { p = a.ps1[0]; h = a.ph1[0]; w = a.wr1[0]; }
        else if (r == 2) { p = a.ps2[0]; h = a.ph2[0]; w = a.wr2[0]; }
        else             { p = a.ps3[0]; h = a.ph3[0]; w = a.wr3[0]; }
        scc[r] = p * h * w * (1.f / (float)NPTS);
    }
    __syncthreads();

    // =====================================================================
    // Encoder. bn1/bn2 stats per n, redundantly over all 16 batches.
    // =====================================================================
    float s1v[4] = {0,0,0,0}, q1v[4] = {0,0,0,0};
    for (int bb = 0; bb < NB; ++bb) {
        const float4* xp = (const float4*)(a.x + (size_t)(bb * NPTS + n0) * 3);
        float4 v0 = xp[0], v1 = xp[1], v2 = xp[2];
        const float xv[12] = { v0.x,v0.y,v0.z, v0.w,v1.x,v1.y,
                               v1.z,v1.w,v2.x, v2.y,v2.z,v2.w };
#pragma unroll
        for (int j = 0; j < 4; ++j)
#pragma unroll
            for (int c = 0; c < 6; ++c) {
                float h = fmaf(w1[c*3], xv[3*j], fmaf(w1[c*3+1], xv[3*j+1],
                          fmaf(w1[c*3+2], xv[3*j+2], b1[c])));
                s1v[j] += h; q1v[j] = fmaf(h, h, q1v[j]);
            }
    }
    float G1[4], E1[4], M1[4];
    {
        const float4 gg = *(const float4*)(a.bn1_g + n0);
        const float4 ee = *(const float4*)(a.bn1_b + n0);
        const float gA[4] = { gg.x, gg.y, gg.z, gg.w };
        const float eA[4] = { ee.x, ee.y, ee.z, ee.w };
#pragma unroll
        for (int j = 0; j < 4; ++j) {
            const float m = s1v[j] * (1.f/96.f);
            const float iv = 1.f / sqrtf(q1v[j]*(1.f/96.f) - m*m + EPSB);
            M1[j] = m; G1[j] = gA[j] * iv; E1[j] = eA[j];
        }
    }

    float s2v[4] = {0,0,0,0}, q2v[4] = {0,0,0,0};
    float h2o[4][12];
    for (int bb = 0; bb < NB; ++bb) {
        const float4* xp = (const float4*)(a.x + (size_t)(bb * NPTS + n0) * 3);
        float4 v0 = xp[0], v1 = xp[1], v2 = xp[2];
        const float xv[12] = { v0.x,v0.y,v0.z, v0.w,v1.x,v1.y,
                               v1.z,v1.w,v2.x, v2.y,v2.z,v2.w };
#pragma unroll
        for (int j = 0; j < 4; ++j) {
            float a1v[6];
#pragma unroll
            for (int c = 0; c < 6; ++c) {
                float h = fmaf(w1[c*3], xv[3*j], fmaf(w1[c*3+1], xv[3*j+1],
                          fmaf(w1[c*3+2], xv[3*j+2], b1[c])));
                a1v[c] = fmaxf(fmaf(h - M1[j], G1[j], E1[j]), 0.f);
            }
#pragma unroll
            for (int c = 0; c < 12; ++c) {
                float h = b2[c];
#pragma unroll
                for (int d = 0; d < 6; ++d) h = fmaf(w2[c*6+d], a1v[d], h);
                s2v[j] += h; q2v[j] = fmaf(h, h, q2v[j]);
                if (bb == batch) h2o[j][c] = h;
            }
        }
    }

    float row[4][12];
    {
        const float4 gg = *(const float4*)(a.bn2_g + n0);
        const float4 ee = *(const float4*)(a.bn2_b + n0);
        const float gA[4] = { gg.x, gg.y, gg.z, gg.w };
        const float eA[4] = { ee.x, ee.y, ee.z, ee.w };
#pragma unroll
        for (int j = 0; j < 4; ++j) {
            const float m = s2v[j] * (1.f/192.f);
            const float iv = 1.f / sqrtf(q2v[j]*(1.f/192.f) - m*m + EPSB);
            const float g2 = gA[j] * iv, e2 = eA[j];
            float a2[12];
#pragma unroll
            for (int c = 0; c < 12; ++c)
                a2[c] = fmaxf(fmaf(h2o[j][c] - m, g2, e2), 0.f);
#pragma unroll
            for (int c = 0; c < 12; ++c) {
                float h = b3[c];
#pragma unroll
                for (int d = 0; d < 12; ++d) h = fmaf(w3[c*12+d], a2[d], h);
                row[j][c] = 1.f / (1.f + expf(-h));
            }
        }
    }

    // =====================================================================
    // 4 relmods, all intra-block.
    // =====================================================================
    const int tile = tid & 3;
    const int xh   = (tile >> 1) * 6;     // M row half
    const int uh   = (tile & 1) * 6;      // M col half
    const int s0   = tid >> 2;            // 0..127 float4-seg base

#pragma unroll 1
    for (int r = 0; r < 4; ++r) {
        // unary for own rows (kept in regs for apply)
        float uR[4][12];
#pragma unroll
        for (int j = 0; j < 4; ++j)
#pragma unroll
            for (int k = 0; k < 12; ++k) {
                float t = Bu[r][k];
#pragma unroll
                for (int d = 0; d < 12; ++d) t = fmaf(Wu[r][k*12+d], row[j][d], t);
                uR[j][k] = fmaxf(t, 0.f);
            }

        float acc[36];
#pragma unroll
        for (int i = 0; i < 36; ++i) acc[i] = 0.f;

#pragma unroll 1
        for (int c = 0; c < 2; ++c) {
            __syncthreads();              // prev chunk reads / Ml reads done
            if ((tid >> 8) == c) {        // this thread's rows live in chunk c
                const int lr = n0 - CROWS * c;
#pragma unroll
                for (int k = 0; k < 12; ++k) {
                    *(float4*)(xT + k*LPC + lr) =
                        make_float4(row[0][k], row[1][k], row[2][k], row[3][k]);
                    *(float4*)(uT + k*LPC + lr) =
                        make_float4(uR[0][k], uR[1][k], uR[2][k], uR[3][k]);
                }
            }
            __syncthreads();
#pragma unroll
            for (int half = 0; half < 2; ++half) {
                const int seg = s0 + 128 * half;
                float4 uv[6];
#pragma unroll
                for (int ee = 0; ee < 6; ++ee)
                    uv[ee] = ((const float4*)(uT + (uh + ee) * LPC))[seg];
#pragma unroll
                for (int dd = 0; dd < 6; ++dd) {
                    const float4 xv4 = ((const float4*)(xT + (xh + dd) * LPC))[seg];
#pragma unroll
                    for (int ee = 0; ee < 6; ++ee) {
                        float m = acc[dd*6+ee];
                        m = fmaf(xv4.x, uv[ee].x, m);
                        m = fmaf(xv4.y, uv[ee].y, m);
                        m = fmaf(xv4.z, uv[ee].z, m);
                        m = fmaf(xv4.w, uv[ee].w, m);
                        acc[dd*6+ee] = m;
                    }
                }
            }
        }
        // butterfly over seg lane bits (2..5), then 8-wave LDS combine
#pragma unroll
        for (int i = 0; i < 36; ++i) {
            float v = acc[i];
            v += __shfl_xor(v, 4);
            v += __shfl_xor(v, 8);
            v += __shfl_xor(v, 16);
            v += __shfl_xor(v, 32);
            acc[i] = v;
        }
        if ((lane & 60) == 0) {
#pragma unroll
            for (int i = 0; i < 36; ++i) Part[wv][tile][i] = acc[i];
        }
        __syncthreads();
        if (tid < 144) {
            const int d = tid / 12, e = tid - d * 12;
            const int qt = ((d >= 6) ? 2 : 0) + ((e >= 6) ? 1 : 0);
            const int rg = (d % 6) * 6 + (e % 6);
            float sm = 0.f;
#pragma unroll
            for (int w = 0; w < 8; ++w) sm += Part[w][qt][rg];
            Ml[tid] = sm;
        }
        __syncthreads();

        // apply in registers
        const float coef = scc[r];
#pragma unroll
        for (int j = 0; j < 4; ++j) {
            float xx = 0.f;
#pragma unroll
            for (int d = 0; d < 12; ++d) xx = fmaf(row[j][d], row[j][d], xx);
            float fo[12];
#pragma unroll
            for (int e = 0; e < 12; ++e) {
                float av = 0.f;
#pragma unroll
                for (int d = 0; d < 12; ++d) av = fmaf(row[j][d], Ml[d*12+e], av);
                fo[e] = fmaf(coef, fmaf(-xx, uR[j][e], av), row[j][e]);
            }
#pragma unroll
            for (int d = 0; d < 12; ++d) row[j][d] = fo[d];
        }
    }

    // =====================================================================
    // fc4 -> bn4 stat partials; single device barrier; fused head.
    // =====================================================================
    float h4[4][6];
#pragma unroll
    for (int j = 0; j < 4; ++j) {
        float ss = 0.f, qq = 0.f;
#pragma unroll
        for (int c = 0; c < 6; ++c) {
            float h = b4[c];
#pragma unroll
            for (int d = 0; d < 12; ++d) h = fmaf(w4[c*12+d], row[j][d], h);
            h4[j][c] = h; ss += h; qq = fmaf(h, h, qq);
        }
        a.G[(size_t)(n0 + j) * NB + batch] = make_float2(ss, qq);
    }

    // ---- all-16-block barrier: release fence + relaxed spin + acquire fence
    __syncthreads();
    if (tid == 0) {
        __threadfence();   // write back partials device-wide
        __hip_atomic_fetch_add(a.cnt, 1, __ATOMIC_RELEASE, __HIP_MEMORY_SCOPE_AGENT);
        while (__hip_atomic_load(a.cnt, __ATOMIC_RELAXED, __HIP_MEMORY_SCOPE_AGENT) < NB)
            __builtin_amdgcn_s_sleep(16);
        __threadfence();   // acquire: see other XCDs' partials
    }
    __syncthreads();

#pragma unroll
    for (int j = 0; j < 4; ++j) {
        const int n = n0 + j;
        const float4* gp = (const float4*)(a.G + (size_t)n * NB);
        float s = 0.f, q = 0.f;
#pragma unroll
        for (int k = 0; k < 8; ++k) {
            const float4 t = gp[k];
            s += t.x + t.z; q += t.y + t.w;
        }
        const float m4 = s * (1.f/96.f);
        const float i4 = 1.f / sqrtf(q*(1.f/96.f) - m4*m4 + EPSB);
        const float g4 = a.bn4_g[n] * i4, e4 = a.bn4_b[n];
        float a4[6];
#pragma unroll
        for (int c = 0; c < 6; ++c)
            a4[c] = fmaxf(fmaf(h4[j][c] - m4, g4, e4), 0.f);
        float a5[3];
#pragma unroll
        for (int c = 0; c < 3; ++c) {
            float h = b5[c];
#pragma unroll
            for (int d = 0; d < 6; ++d) h = fmaf(w5[c*6+d], a4[d], h);
            a5[c] = fmaxf(h, 0.f);
        }
        float* op = a.out + (size_t)(batch * NPTS + n) * 3;
        op[0] = fmaf(w6[0], a5[0], fmaf(w6[1], a5[1], fmaf(w6[2], a5[2], hb[0])));
        op[1] = fmaf(w7[0], a5[0], fmaf(w7[1], a5[1], fmaf(w7[2], a5[2], hb[1])));
        op[2] = fmaf(w7[3], a5[0], fmaf(w7[4], a5[1], fmaf(w7[5], a5[2], hb[2])));
    }
}

// ---------------------------------------------------------------------------
extern "C" void kernel_launch(void* const* d_in, const int* in_sizes, int n_in,
                              void* d_out, int out_size, void* d_ws, size_t ws_size,
                              hipStream_t stream)
{
    KArgs ka;
    ka.x     = (const float*)d_in[0];
    ka.fc1_w = (const float*)d_in[1];  ka.fc1_b = (const float*)d_in[2];
    ka.bn1_g = (const float*)d_in[3];  ka.bn1_b = (const float*)d_in[4];
    ka.fc2_w = (const float*)d_in[5];  ka.fc2_b = (const float*)d_in[6];
    ka.bn2_g = (const float*)d_in[7];  ka.bn2_b = (const float*)d_in[8];
    ka.fc3_w = (const float*)d_in[9];  ka.fc3_b = (const float*)d_in[10];
    ka.uw0 = (const float*)d_in[11]; ka.ub0 = (const float*)d_in[12];
    ka.ps0 = (const float*)d_in[13]; ka.ph0 = (const float*)d_in[14]; ka.wr0 = (const float*)d_in[15];
    ka.uw1 = (const float*)d_in[16]; ka.ub1 = (const float*)d_in[17];
    ka.ps1 = (const float*)d_in[18]; ka.ph1 = (const float*)d_in[19]; ka.wr1 = (const float*)d_in[20];
    ka.uw2 = (const float*)d_in[21]; ka.ub2 = (const float*)d_in[22];
    ka.ps2 = (const float*)d_in[23]; ka.ph2 = (const float*)d_in[24]; ka.wr2 = (const float*)d_in[25];
    ka.uw3 = (const float*)d_in[26]; ka.ub3 = (const float*)d_in[27];
    ka.ps3 = (const float*)d_in[28]; ka.ph3 = (const float*)d_in[29]; ka.wr3 = (const float*)d_in[30];
    ka.fc4_w = (const float*)d_in[31]; ka.fc4_b = (const float*)d_in[32];
    ka.bn4_g = (const float*)d_in[33]; ka.bn4_b = (const float*)d_in[34];
    ka.fc5_w = (const float*)d_in[35]; ka.fc5_b = (const float*)d_in[36];
    ka.fc6_w = (const float*)d_in[37]; ka.fc6_b = (const float*)d_in[38];
    ka.fc7_w = (const float*)d_in[39]; ka.fc7_b = (const float*)d_in[40];

    float* ws = (float*)d_ws;
    ka.cnt = (int*)ws;                      // arrive counter (own 256 B region)
    ka.G   = (float2*)(ws + 64);            // [2048][16] float2 = 256 KB
    ka.out = (float*)d_out;

    hipMemsetAsync(ka.cnt, 0, 64, stream);  // re-zero counter every call
    relnet_one<<<dim3(NB), dim3(NT), 0, stream>>>(ka);
}